// Round 11
// baseline (51.192 us; speedup 1.0000x reference)
//
#include <hip/hip_runtime.h>
#include <hip/hip_bf16.h>

typedef __attribute__((ext_vector_type(4))) float f32x4;
typedef __attribute__((ext_vector_type(8))) __bf16 bf16x8;
typedef __attribute__((ext_vector_type(4))) __bf16 bf16x4;

#define B_DIM 16
#define L_DIM 1024
#define D_DIM 256

// ---------------------------------------------------------------------------
// Prep: row norms + fp32->bf16 conversion in one pass (r4/r9-proven).
// ---------------------------------------------------------------------------
__global__ __launch_bounds__(256) void prep_kernel(const float* __restrict__ s1,
                                                   const float* __restrict__ s2,
                                                   float* __restrict__ nrm,
                                                   __hip_bfloat16* __restrict__ s1b,
                                                   __hip_bfloat16* __restrict__ s2b) {
    const int w = threadIdx.x >> 6, l = threadIdx.x & 63;
    const int base = (blockIdx.x << 4) + (w << 2);  // 16 rows/block, 4/wave
#pragma unroll
    for (int i = 0; i < 4; ++i) {
        const int row = base + i;          // 0 .. 32767
        const int second = row >> 14;      // rows >= 16384 are s2 (wave-uniform)
        const int r = row & 16383;
        const float* src = (second ? s2 : s1) + (size_t)r * D_DIM;
        __hip_bfloat16* dst = (second ? s2b : s1b) + (size_t)r * D_DIM;
        float4 v = reinterpret_cast<const float4*>(src)[l];
        float s = v.x * v.x + v.y * v.y + v.z * v.z + v.w * v.w;
        bf16x4 bv;
        bv[0] = (__bf16)v.x; bv[1] = (__bf16)v.y; bv[2] = (__bf16)v.z; bv[3] = (__bf16)v.w;
        *reinterpret_cast<bf16x4*>(dst + l * 4) = bv;
#pragma unroll
        for (int o = 32; o > 0; o >>= 1) s += __shfl_xor(s, o, 64);
        if (l == 0) nrm[row] = s;
    }
}

// ---------------------------------------------------------------------------
// Direct-from-cache GEMM: NO LDS, NO barriers. The 16x16x32 MFMA A/B frag is
// 16B contiguous in global per lane (lane l: row l&15 (+16m), k-slot l>>4),
// so frags load straight from the L2/L3-resident bf16 workspace with
// global_load_dwordx4. Double-buffered frag registers: load kt+1 while
// MFMAing kt (compiler inserts the precise vmcnt). Waves free-run; loads,
// MFMA, and the output store stream overlap via TLP (3 blocks/CU).
// ---------------------------------------------------------------------------
__global__ __launch_bounds__(256, 3) void dist_gemm_direct_kernel(const __hip_bfloat16* __restrict__ s1b,
                                                                  const __hip_bfloat16* __restrict__ s2b,
                                                                  const float* __restrict__ nrm,
                                                                  float* __restrict__ out) {
    const int t = threadIdx.x;
    const int p = blockIdx.x;
    // XCD swizzle: XCD x owns logical tiles [128x,128x+128) = 2 batches.
    const int d = ((p & 7) << 7) + (p >> 3);  // bijective for 1024 blocks
    const int batch = d >> 6;
    const int tile = d & 63;
    const int row0 = (tile >> 3) << 7;
    const int col0 = (tile & 7) << 7;

    const int l = t & 63, w = t >> 6;
    const int wr = w >> 1, wc = w & 1;   // wave -> 64x64 quadrant
    const int lr = l & 15;               // frag row (A) / col (B,C)
    const int lq = l >> 4;               // k-slot (8 bf16 = 16B)

    // per-lane frag base pointers (16B-aligned; rows are 512B apart)
    const __hip_bfloat16* Abase =
        s1b + ((size_t)batch * L_DIM + row0 + (wr << 6) + lr) * D_DIM + (lq << 3);
    const __hip_bfloat16* Bbase =
        s2b + ((size_t)batch * L_DIM + col0 + (wc << 6) + lr) * D_DIM + (lq << 3);

    // norm preload (overlaps the first frag loads)
    const float* x2 = nrm + batch * L_DIM;
    const float* y2 = nrm + B_DIM * L_DIM + batch * L_DIM;
    const int rbase = row0 + (wr << 6) + (lq << 2);
    const int cbase = col0 + (wc << 6) + lr;
    f32x4 xv[4]; float yv[4];
#pragma unroll
    for (int m = 0; m < 4; ++m) xv[m] = *reinterpret_cast<const f32x4*>(&x2[rbase + (m << 4)]);
#pragma unroll
    for (int n = 0; n < 4; ++n) yv[n] = y2[cbase + (n << 4)];

    f32x4 acc[4][4] = {};
    bf16x8 aF[2][4], bF[2][4];

    auto loadFrags = [&](int kt, bf16x8* a, bf16x8* b) {  // 8 x global_load_dwordx4
        const int ko = kt << 5;
#pragma unroll
        for (int m = 0; m < 4; ++m)
            a[m] = *reinterpret_cast<const bf16x8*>(Abase + (size_t)(m << 4) * D_DIM + ko);
#pragma unroll
        for (int n = 0; n < 4; ++n)
            b[n] = *reinterpret_cast<const bf16x8*>(Bbase + (size_t)(n << 4) * D_DIM + ko);
    };

    loadFrags(0, aF[0], bF[0]);
#pragma unroll
    for (int kt = 0; kt < 8; ++kt) {
        if (kt < 7) loadFrags(kt + 1, aF[(kt + 1) & 1], bF[(kt + 1) & 1]);
        __builtin_amdgcn_s_setprio(1);
#pragma unroll
        for (int m = 0; m < 4; ++m)
#pragma unroll
            for (int n = 0; n < 4; ++n)
                acc[m][n] = __builtin_amdgcn_mfma_f32_16x16x32_bf16(
                    aF[kt & 1][m], bF[kt & 1][n], acc[m][n], 0, 0, 0);
        __builtin_amdgcn_s_setprio(0);
    }

    // epilogue: out = 1/(1+sqrt(max(x2+y2-2xy,0)))
    float* outb = out + (size_t)batch * L_DIM * L_DIM;
#pragma unroll
    for (int n = 0; n < 4; ++n) {
        const int col = cbase + (n << 4);
        const float y2v = yv[n];
#pragma unroll
        for (int m = 0; m < 4; ++m) {
#pragma unroll
            for (int r = 0; r < 4; ++r) {
                const int row = rbase + (m << 4) + r;
                float sq = fmaxf(xv[m][r] + y2v - 2.0f * acc[m][n][r], 0.0f);
                outb[(size_t)row * L_DIM + col] =
                    __builtin_amdgcn_rcpf(1.0f + __builtin_amdgcn_sqrtf(sq));
            }
        }
    }
}

// ---------------------------------------------------------------------------
// Fallback path for the case ws_size < needed.
// ---------------------------------------------------------------------------
__global__ __launch_bounds__(256) void norms_kernel(const float* __restrict__ s1,
                                                    const float* __restrict__ s2,
                                                    float* __restrict__ nrm) {
    int w = threadIdx.x >> 6, l = threadIdx.x & 63;
    int row = (blockIdx.x << 2) + w;
    const float* src = (row < B_DIM * L_DIM)
                           ? (s1 + (size_t)row * D_DIM)
                           : (s2 + (size_t)(row - B_DIM * L_DIM) * D_DIM);
    float4 v = reinterpret_cast<const float4*>(src)[l];
    float s = v.x * v.x + v.y * v.y + v.z * v.z + v.w * v.w;
#pragma unroll
    for (int o = 32; o > 0; o >>= 1) s += __shfl_xor(s, o, 64);
    if (l == 0) nrm[row] = s;
}

__global__ __launch_bounds__(256) void dist_gemm_kernel(const float* __restrict__ s1,
                                                        const float* __restrict__ s2,
                                                        const float* __restrict__ nrm,
                                                        float* __restrict__ out) {
    __shared__ __bf16 Alds[2][128 * 32];
    __shared__ __bf16 Blds[2][128 * 32];

    const int t = threadIdx.x;
    const int p = blockIdx.x;
    const int d = ((p & 7) << 7) + (p >> 3);
    const int batch = d >> 6;
    const int tile = d & 63;
    const int row0 = (tile >> 3) << 7;
    const int col0 = (tile & 7) << 7;

    const float* Ag = s1 + ((size_t)batch * L_DIM + row0) * D_DIM;
    const float* Bg = s2 + ((size_t)batch * L_DIM + col0) * D_DIM;

    const int sr = t >> 2;
    const int sc = (t & 3) << 3;

    const int l = t & 63, w = t >> 6;
    const int wr = w >> 1, wc = w & 1;
    const int lr = l & 15;
    const int lk = (l >> 4) << 3;

    f32x4 acc[4][4] = {};

    auto stage = [&](int buf, int k0) {
#pragma unroll
        for (int pass = 0; pass < 2; ++pass) {
            const int r = sr + (pass << 6);
            const float4* sa = reinterpret_cast<const float4*>(Ag + (size_t)r * D_DIM + k0 + sc);
            float4 a0 = sa[0], a1 = sa[1];
            const float4* sb = reinterpret_cast<const float4*>(Bg + (size_t)r * D_DIM + k0 + sc);
            float4 b0 = sb[0], b1 = sb[1];
            bf16x8 av, bv;
            av[0] = (__bf16)a0.x; av[1] = (__bf16)a0.y; av[2] = (__bf16)a0.z; av[3] = (__bf16)a0.w;
            av[4] = (__bf16)a1.x; av[5] = (__bf16)a1.y; av[6] = (__bf16)a1.z; av[7] = (__bf16)a1.w;
            bv[0] = (__bf16)b0.x; bv[1] = (__bf16)b0.y; bv[2] = (__bf16)b0.z; bv[3] = (__bf16)b0.w;
            bv[4] = (__bf16)b1.x; bv[5] = (__bf16)b1.y; bv[6] = (__bf16)b1.z; bv[7] = (__bf16)b1.w;
            *reinterpret_cast<bf16x8*>(&Alds[buf][(r << 5) + sc]) = av;
            *reinterpret_cast<bf16x8*>(&Blds[buf][(r << 5) + sc]) = bv;
        }
    };

    stage(0, 0);
    __syncthreads();
    int cur = 0;
    for (int kt = 0; kt < 8; ++kt) {
        if (kt < 7) stage(cur ^ 1, (kt + 1) << 5);
        bf16x8 aF[4], bF[4];
#pragma unroll
        for (int m = 0; m < 4; ++m)
            aF[m] = *reinterpret_cast<const bf16x8*>(
                &Alds[cur][(((wr << 6) + (m << 4) + lr) << 5) + lk]);
#pragma unroll
        for (int n = 0; n < 4; ++n)
            bF[n] = *reinterpret_cast<const bf16x8*>(
                &Blds[cur][(((wc << 6) + (n << 4) + lr) << 5) + lk]);
#pragma unroll
        for (int m = 0; m < 4; ++m)
#pragma unroll
            for (int n = 0; n < 4; ++n)
                acc[m][n] = __builtin_amdgcn_mfma_f32_16x16x32_bf16(aF[m], bF[n], acc[m][n], 0, 0, 0);
        __syncthreads();
        cur ^= 1;
    }

    const float* x2 = nrm + batch * L_DIM;
    const float* y2 = nrm + B_DIM * L_DIM + batch * L_DIM;
    float* outb = out + (size_t)batch * L_DIM * L_DIM;
    const int rbase = row0 + (wr << 6) + ((l >> 4) << 2);
    const int cbase = col0 + (wc << 6) + lr;
#pragma unroll
    for (int n = 0; n < 4; ++n) {
        const int col = cbase + (n << 4);
        const float y2v = y2[col];
#pragma unroll
        for (int m = 0; m < 4; ++m) {
            const int rowf = rbase + (m << 4);
#pragma unroll
            for (int r = 0; r < 4; ++r) {
                const int row = rowf + r;
                float sq = x2[row] + y2v - 2.0f * acc[m][n][r];
                sq = fmaxf(sq, 0.0f);
                outb[(size_t)row * L_DIM + col] = 1.0f / (1.0f + sqrtf(sq));
            }
        }
    }
}

extern "C" void kernel_launch(void* const* d_in, const int* in_sizes, int n_in,
                              void* d_out, int out_size, void* d_ws, size_t ws_size,
                              hipStream_t stream) {
    (void)in_sizes; (void)n_in; (void)out_size;
    const float* s1 = (const float*)d_in[1];
    const float* s2 = (const float*)d_in[2];
    float* out = (float*)d_out;

    const size_t NRM_BYTES = 2u * B_DIM * L_DIM * sizeof(float);          // 128 KB
    const size_t BF_BYTES = (size_t)B_DIM * L_DIM * D_DIM * sizeof(__hip_bfloat16);  // 8 MB each
    const size_t NEED = NRM_BYTES + 2 * BF_BYTES;                          // ~16.9 MB

    float* nrm = (float*)d_ws;
    if (ws_size >= NEED) {
        __hip_bfloat16* s1b = (__hip_bfloat16*)((char*)d_ws + NRM_BYTES);
        __hip_bfloat16* s2b = (__hip_bfloat16*)((char*)d_ws + NRM_BYTES + BF_BYTES);
        prep_kernel<<<2048, 256, 0, stream>>>(s1, s2, nrm, s1b, s2b);
        dist_gemm_direct_kernel<<<1024, 256, 0, stream>>>(s1b, s2b, nrm, out);
    } else {
        norms_kernel<<<8192, 256, 0, stream>>>(s1, s2, nrm);
        dist_gemm_kernel<<<1024, 256, 0, stream>>>(s1, s2, nrm, out);
    }
}

// Round 12
// 38.109 us; speedup vs baseline: 1.3433x; 1.3433x over previous
//
#include <hip/hip_runtime.h>
#include <hip/hip_bf16.h>

typedef __attribute__((ext_vector_type(4))) float f32x4;
typedef __attribute__((ext_vector_type(8))) __bf16 bf16x8;
typedef __attribute__((ext_vector_type(4))) __bf16 bf16x4;

#define B_DIM 16
#define L_DIM 1024
#define D_DIM 256

#define GLOAD_LDS16(g, lptr)                                          \
    __builtin_amdgcn_global_load_lds(                                 \
        (const __attribute__((address_space(1))) void*)(g),           \
        (__attribute__((address_space(3))) void*)(lptr), 16, 0, 0)

#define SBAR() __builtin_amdgcn_sched_barrier(0)

// ---------------------------------------------------------------------------
// Prep: row norms + fp32->bf16 conversion in one pass (r4/r9-proven).
// ---------------------------------------------------------------------------
__global__ __launch_bounds__(256) void prep_kernel(const float* __restrict__ s1,
                                                   const float* __restrict__ s2,
                                                   float* __restrict__ nrm,
                                                   __hip_bfloat16* __restrict__ s1b,
                                                   __hip_bfloat16* __restrict__ s2b) {
    const int w = threadIdx.x >> 6, l = threadIdx.x & 63;
    const int base = (blockIdx.x << 4) + (w << 2);  // 16 rows/block, 4/wave
#pragma unroll
    for (int i = 0; i < 4; ++i) {
        const int row = base + i;          // 0 .. 32767
        const int second = row >> 14;      // rows >= 16384 are s2 (wave-uniform)
        const int r = row & 16383;
        const float* src = (second ? s2 : s1) + (size_t)r * D_DIM;
        __hip_bfloat16* dst = (second ? s2b : s1b) + (size_t)r * D_DIM;
        float4 v = reinterpret_cast<const float4*>(src)[l];
        float s = v.x * v.x + v.y * v.y + v.z * v.z + v.w * v.w;
        bf16x4 bv;
        bv[0] = (__bf16)v.x; bv[1] = (__bf16)v.y; bv[2] = (__bf16)v.z; bv[3] = (__bf16)v.w;
        *reinterpret_cast<bf16x4*>(dst + l * 4) = bv;
#pragma unroll
        for (int o = 32; o > 0; o >>= 1) s += __shfl_xor(s, o, 64);
        if (l == 0) nrm[row] = s;
    }
}

// ---------------------------------------------------------------------------
// Hybrid persistent 2-tile GEMM (r9 skeleton):
//  - A frags: DIRECT per-lane global_load_dwordx4 from L2-resident workspace,
//    streamed 2 steps ahead into a 3-slot register ring (no LDS for A).
//  - B: r9-proven 4-buffer LDS pipeline (2 gload_lds/stage, 4 ds_read/frags,
//    lgkmcnt(4), one barrier per step).
//  - Tile1 overlaps tile0's 64-store epilogue (r9-proven placement).
// vmcnt streams (in-order retire), per step kt issues [A(kt+2):4][st(kt+3):2]:
//  prologue: xv/yv(12) A0(4) A1(4) st0(2) st1(2) st2(2) -> vmcnt(2) keeps st2.
//  tile0 kt=1..5: keep A(kt+1)+st(kt+2)=6 -> vmcnt(6); kt=6: keep A7 -> 4; kt=7: 0.
//  transition: st0'-2'(6) A0'(4) A1'(4) stores(64)=78 -> vmcnt(63) drains
//    st0'-2'+A0'+A1' (+1 store), 63 stores stay in flight.
//  tile1 kt=1: nothing needed (all drained) -> barrier only;
//  kt=2..5: vmcnt(6) (drains remaining stores, r9-proven OK); kt=6: 4; kt=7: 0.
// LDS overwrite safety: identical to r9 (buf b last-read drained by lgkm wait
// 1+ steps earlier, ordered by the per-step barriers).
// ---------------------------------------------------------------------------
__global__ __launch_bounds__(256, 2) void dist_gemm2_kernel(const __hip_bfloat16* __restrict__ s1b,
                                                            const __hip_bfloat16* __restrict__ s2b,
                                                            const float* __restrict__ nrm,
                                                            float* __restrict__ out) {
    __shared__ __bf16 Blds[4][128 * 32];   // B only: 32 KB

    const int t = threadIdx.x;
    const int p = blockIdx.x;
    // XCD swizzle (512 blocks): XCD x owns d in [64x,64x+64) = batches 2x,2x+1.
    const int d = ((p & 7) << 6) + (p >> 3);
    const int batch = d >> 5;
    const int rem = d & 31;                    // 8 row-panels x 4 col-pairs
    const int row0 = (rem >> 2) << 7;
    const int col0a = (rem & 3) << 8;
    const int col0b = col0a + 128;

    const __hip_bfloat16* Bg0 = s2b + ((size_t)batch * L_DIM + col0a) * D_DIM;
    const __hip_bfloat16* Bg1 = s2b + ((size_t)batch * L_DIM + col0b) * D_DIM;

    const int l = t & 63, w = t >> 6;
    const int wr = w >> 1, wc = w & 1;   // wave -> 64x64 quadrant
    const int lr = l & 15;               // frag row (A) / col (B,C)
    const int lq = l >> 4;               // k-slot (16B)

    // A per-lane frag base: lane holds row (wr*64 + m*16 + lr), k-slot lq.
    const __hip_bfloat16* Abase =
        s1b + ((size_t)batch * L_DIM + row0 + (wr << 6) + lr) * D_DIM + (lq << 3);

    const int srow_in_seg = l >> 2;
    const int sslot = (l & 3) ^ ((l >> 3) & 3);

    auto stageB = [&](const __hip_bfloat16* Bg, int kt) {  // 2 gload_lds
        const int k0 = kt << 5;
        const int b = kt & 3;
#pragma unroll
        for (int i = 0; i < 2; ++i) {
            const int s = (w << 1) | i;
            const int rl = (s << 4) + srow_in_seg;
            GLOAD_LDS16(Bg + rl * D_DIM + k0 + sslot * 8, &Blds[b][s << 9]);
        }
    };

    bf16x8 aA[3][4];                      // A ring: aA[kt%3]
    auto loadA = [&](int kt) {            // 4 global_load_dwordx4
        const int ko = kt << 5;
        bf16x8* dst = aA[kt % 3];
#pragma unroll
        for (int m = 0; m < 4; ++m)
            dst[m] = *reinterpret_cast<const bf16x8*>(Abase + (size_t)(m << 4) * D_DIM + ko);
    };

    bf16x8 bF[2][4];
    auto readFragsB = [&](int kt, bf16x8* bfr) {  // 4 ds_read_b128
        const int b = kt & 3;
#pragma unroll
        for (int n = 0; n < 4; ++n) {
            const int row = (wc << 6) + (n << 4) + lr;
            const int sl = lq ^ ((row >> 1) & 3);
            bfr[n] = *reinterpret_cast<const bf16x8*>(&Blds[b][(row << 5) + (sl << 3)]);
        }
    };

    const float* x2 = nrm + batch * L_DIM;
    const float* y2 = nrm + B_DIM * L_DIM + batch * L_DIM;
    const int rbase = row0 + (wr << 6) + (lq << 2);
    const int cloc = (wc << 6) + lr;
    float* outb = out + (size_t)batch * L_DIM * L_DIM;

    auto epilogue = [&](const f32x4 (&acc)[4][4], const f32x4 (&xv)[4],
                        const float (&yv)[4], int col0_) {
        const int cb = col0_ + cloc;
#pragma unroll
        for (int n = 0; n < 4; ++n) {
            const int col = cb + (n << 4);
            const float y2v = yv[n];
#pragma unroll
            for (int m = 0; m < 4; ++m) {
#pragma unroll
                for (int r = 0; r < 4; ++r) {
                    const int row = rbase + (m << 4) + r;
                    float sq = fmaxf(xv[m][r] + y2v - 2.0f * acc[m][n][r], 0.0f);
                    outb[(size_t)row * L_DIM + col] =
                        __builtin_amdgcn_rcpf(1.0f + __builtin_amdgcn_sqrtf(sq));
                }
            }
        }
    };

    // ===================== PROLOGUE ========================================
    f32x4 xv[4]; float yv0[4], yv1[4];
#pragma unroll
    for (int m = 0; m < 4; ++m) xv[m] = *reinterpret_cast<const f32x4*>(&x2[rbase + (m << 4)]);
#pragma unroll
    for (int n = 0; n < 4; ++n) yv0[n] = y2[col0a + cloc + (n << 4)];
#pragma unroll
    for (int n = 0; n < 4; ++n) yv1[n] = y2[col0b + cloc + (n << 4)];
    SBAR();
    loadA(0); loadA(1);
    SBAR();
    f32x4 acc0[4][4] = {};
    stageB(Bg0, 0); stageB(Bg0, 1); stageB(Bg0, 2);
    SBAR();
    asm volatile("s_waitcnt vmcnt(2)" ::: "memory");   // all but st2 landed
    __builtin_amdgcn_s_barrier();
    readFragsB(0, bF[0]);

    // ===================== TILE 0 K-LOOP ===================================
#pragma unroll
    for (int kt = 0; kt < 8; ++kt) {
        if (kt >= 1) {
            if (kt <= 5)      asm volatile("s_waitcnt vmcnt(6)" ::: "memory");
            else if (kt == 6) asm volatile("s_waitcnt vmcnt(4)" ::: "memory");
            else              asm volatile("s_waitcnt vmcnt(0)" ::: "memory");
            __builtin_amdgcn_s_barrier();
        }
        if (kt < 7) readFragsB(kt + 1, bF[(kt + 1) & 1]);
        if (kt < 7) asm volatile("s_waitcnt lgkmcnt(4)" ::: "memory");
        else        asm volatile("s_waitcnt lgkmcnt(0)" ::: "memory");
        if (kt <= 5) loadA(kt + 2);
        if (kt <= 4) stageB(Bg0, kt + 3);
        __builtin_amdgcn_s_setprio(1);
#pragma unroll
        for (int m = 0; m < 4; ++m)
#pragma unroll
            for (int n = 0; n < 4; ++n)
                acc0[m][n] = __builtin_amdgcn_mfma_f32_16x16x32_bf16(
                    aA[kt % 3][m], bF[kt & 1][n], acc0[m][n], 0, 0, 0);
        __builtin_amdgcn_s_setprio(0);
    }

    // ===================== TRANSITION ======================================
    stageB(Bg1, 0); stageB(Bg1, 1); stageB(Bg1, 2);
    SBAR();
    loadA(0); loadA(1);                      // same addrs, L2-hot
    SBAR();
    epilogue(acc0, xv, yv0, col0a);          // 64 fire-and-forget stores
    SBAR();
    asm volatile("s_waitcnt vmcnt(63)" ::: "memory");  // drains st0'-2',A0',A1'
    __builtin_amdgcn_s_barrier();
    f32x4 acc1[4][4] = {};
    readFragsB(0, bF[0]);

    // ===================== TILE 1 K-LOOP ===================================
#pragma unroll
    for (int kt = 0; kt < 8; ++kt) {
        if (kt >= 1) {
            if (kt >= 2 && kt <= 5) asm volatile("s_waitcnt vmcnt(6)" ::: "memory");
            else if (kt == 6)       asm volatile("s_waitcnt vmcnt(4)" ::: "memory");
            else if (kt == 7)       asm volatile("s_waitcnt vmcnt(0)" ::: "memory");
            __builtin_amdgcn_s_barrier();
        }
        if (kt < 7) readFragsB(kt + 1, bF[(kt + 1) & 1]);
        if (kt < 7) asm volatile("s_waitcnt lgkmcnt(4)" ::: "memory");
        else        asm volatile("s_waitcnt lgkmcnt(0)" ::: "memory");
        if (kt <= 5) loadA(kt + 2);
        if (kt <= 4) stageB(Bg1, kt + 3);
        __builtin_amdgcn_s_setprio(1);
#pragma unroll
        for (int m = 0; m < 4; ++m)
#pragma unroll
            for (int n = 0; n < 4; ++n)
                acc1[m][n] = __builtin_amdgcn_mfma_f32_16x16x32_bf16(
                    aA[kt % 3][m], bF[kt & 1][n], acc1[m][n], 0, 0, 0);
        __builtin_amdgcn_s_setprio(0);
    }

    epilogue(acc1, xv, yv1, col0b);
}

// ---------------------------------------------------------------------------
// Fallback path for the case ws_size < needed.
// ---------------------------------------------------------------------------
__global__ __launch_bounds__(256) void norms_kernel(const float* __restrict__ s1,
                                                    const float* __restrict__ s2,
                                                    float* __restrict__ nrm) {
    int w = threadIdx.x >> 6, l = threadIdx.x & 63;
    int row = (blockIdx.x << 2) + w;
    const float* src = (row < B_DIM * L_DIM)
                           ? (s1 + (size_t)row * D_DIM)
                           : (s2 + (size_t)(row - B_DIM * L_DIM) * D_DIM);
    float4 v = reinterpret_cast<const float4*>(src)[l];
    float s = v.x * v.x + v.y * v.y + v.z * v.z + v.w * v.w;
#pragma unroll
    for (int o = 32; o > 0; o >>= 1) s += __shfl_xor(s, o, 64);
    if (l == 0) nrm[row] = s;
}

__global__ __launch_bounds__(256) void dist_gemm_kernel(const float* __restrict__ s1,
                                                        const float* __restrict__ s2,
                                                        const float* __restrict__ nrm,
                                                        float* __restrict__ out) {
    __shared__ __bf16 Alds[2][128 * 32];
    __shared__ __bf16 Blds2[2][128 * 32];

    const int t = threadIdx.x;
    const int p = blockIdx.x;
    const int d = ((p & 7) << 7) + (p >> 3);
    const int batch = d >> 6;
    const int tile = d & 63;
    const int row0 = (tile >> 3) << 7;
    const int col0 = (tile & 7) << 7;

    const float* Ag = s1 + ((size_t)batch * L_DIM + row0) * D_DIM;
    const float* Bg = s2 + ((size_t)batch * L_DIM + col0) * D_DIM;

    const int sr = t >> 2;
    const int sc = (t & 3) << 3;

    const int l = t & 63, w = t >> 6;
    const int wr = w >> 1, wc = w & 1;
    const int lr = l & 15;
    const int lk = (l >> 4) << 3;

    f32x4 acc[4][4] = {};

    auto stage = [&](int buf, int k0) {
#pragma unroll
        for (int pass = 0; pass < 2; ++pass) {
            const int r = sr + (pass << 6);
            const float4* sa = reinterpret_cast<const float4*>(Ag + (size_t)r * D_DIM + k0 + sc);
            float4 a0 = sa[0], a1 = sa[1];
            const float4* sb = reinterpret_cast<const float4*>(Bg + (size_t)r * D_DIM + k0 + sc);
            float4 b0 = sb[0], b1 = sb[1];
            bf16x8 av, bv;
            av[0] = (__bf16)a0.x; av[1] = (__bf16)a0.y; av[2] = (__bf16)a0.z; av[3] = (__bf16)a0.w;
            av[4] = (__bf16)a1.x; av[5] = (__bf16)a1.y; av[6] = (__bf16)a1.z; av[7] = (__bf16)a1.w;
            bv[0] = (__bf16)b0.x; bv[1] = (__bf16)b0.y; bv[2] = (__bf16)b0.z; bv[3] = (__bf16)b0.w;
            bv[4] = (__bf16)b1.x; bv[5] = (__bf16)b1.y; bv[6] = (__bf16)b1.z; bv[7] = (__bf16)b1.w;
            *reinterpret_cast<bf16x8*>(&Alds[buf][(r << 5) + sc]) = av;
            *reinterpret_cast<bf16x8*>(&Blds2[buf][(r << 5) + sc]) = bv;
        }
    };

    stage(0, 0);
    __syncthreads();
    int cur = 0;
    for (int kt = 0; kt < 8; ++kt) {
        if (kt < 7) stage(cur ^ 1, (kt + 1) << 5);
        bf16x8 aF[4], bF[4];
#pragma unroll
        for (int m = 0; m < 4; ++m)
            aF[m] = *reinterpret_cast<const bf16x8*>(
                &Alds[cur][(((wr << 6) + (m << 4) + lr) << 5) + lk]);
#pragma unroll
        for (int n = 0; n < 4; ++n)
            bF[n] = *reinterpret_cast<const bf16x8*>(
                &Blds2[cur][(((wc << 6) + (n << 4) + lr) << 5) + lk]);
#pragma unroll
        for (int m = 0; m < 4; ++m)
#pragma unroll
            for (int n = 0; n < 4; ++n)
                acc[m][n] = __builtin_amdgcn_mfma_f32_16x16x32_bf16(aF[m], bF[n], acc[m][n], 0, 0, 0);
        __syncthreads();
        cur ^= 1;
    }

    const float* x2 = nrm + batch * L_DIM;
    const float* y2 = nrm + B_DIM * L_DIM + batch * L_DIM;
    float* outb = out + (size_t)batch * L_DIM * L_DIM;
    const int rbase = row0 + (wr << 6) + ((l >> 4) << 2);
    const int cbase = col0 + (wc << 6) + lr;
#pragma unroll
    for (int n = 0; n < 4; ++n) {
        const int col = cbase + (n << 4);
        const float y2v = y2[col];
#pragma unroll
        for (int m = 0; m < 4; ++m) {
            const int rowf = rbase + (m << 4);
#pragma unroll
            for (int r = 0; r < 4; ++r) {
                const int row = rowf + r;
                float sq = x2[row] + y2v - 2.0f * acc[m][n][r];
                sq = fmaxf(sq, 0.0f);
                outb[(size_t)row * L_DIM + col] = 1.0f / (1.0f + sqrtf(sq));
            }
        }
    }
}

extern "C" void kernel_launch(void* const* d_in, const int* in_sizes, int n_in,
                              void* d_out, int out_size, void* d_ws, size_t ws_size,
                              hipStream_t stream) {
    (void)in_sizes; (void)n_in; (void)out_size;
    const float* s1 = (const float*)d_in[1];
    const float* s2 = (const float*)d_in[2];
    float* out = (float*)d_out;

    const size_t NRM_BYTES = 2u * B_DIM * L_DIM * sizeof(float);          // 128 KB
    const size_t BF_BYTES = (size_t)B_DIM * L_DIM * D_DIM * sizeof(__hip_bfloat16);  // 8 MB each
    const size_t NEED = NRM_BYTES + 2 * BF_BYTES;                          // ~16.9 MB

    float* nrm = (float*)d_ws;
    if (ws_size >= NEED) {
        __hip_bfloat16* s1b = (__hip_bfloat16*)((char*)d_ws + NRM_BYTES);
        __hip_bfloat16* s2b = (__hip_bfloat16*)((char*)d_ws + NRM_BYTES + BF_BYTES);
        prep_kernel<<<2048, 256, 0, stream>>>(s1, s2, nrm, s1b, s2b);
        dist_gemm2_kernel<<<512, 256, 0, stream>>>(s1b, s2b, nrm, out);
    } else {
        norms_kernel<<<8192, 256, 0, stream>>>(s1, s2, nrm);
        dist_gemm_kernel<<<1024, 256, 0, stream>>>(s1, s2, nrm, out);
    }
}

// Round 13
// 32.089 us; speedup vs baseline: 1.5953x; 1.1876x over previous
//
#include <hip/hip_runtime.h>
#include <hip/hip_bf16.h>

typedef __attribute__((ext_vector_type(4))) float f32x4;
typedef __attribute__((ext_vector_type(8))) __bf16 bf16x8;
typedef __attribute__((ext_vector_type(4))) __bf16 bf16x4;

#define B_DIM 16
#define L_DIM 1024
#define D_DIM 256

#define GLOAD_LDS16(g, lptr)                                          \
    __builtin_amdgcn_global_load_lds(                                 \
        (const __attribute__((address_space(1))) void*)(g),           \
        (__attribute__((address_space(3))) void*)(lptr), 16, 0, 0)

#define SBAR() __builtin_amdgcn_sched_barrier(0)

// ---------------------------------------------------------------------------
// Prep: row norms + fp32->bf16 conversion in one pass (r4/r9-proven).
// ---------------------------------------------------------------------------
__global__ __launch_bounds__(256) void prep_kernel(const float* __restrict__ s1,
                                                   const float* __restrict__ s2,
                                                   float* __restrict__ nrm,
                                                   __hip_bfloat16* __restrict__ s1b,
                                                   __hip_bfloat16* __restrict__ s2b) {
    const int w = threadIdx.x >> 6, l = threadIdx.x & 63;
    const int base = (blockIdx.x << 4) + (w << 2);  // 16 rows/block, 4/wave
#pragma unroll
    for (int i = 0; i < 4; ++i) {
        const int row = base + i;          // 0 .. 32767
        const int second = row >> 14;      // rows >= 16384 are s2 (wave-uniform)
        const int r = row & 16383;
        const float* src = (second ? s2 : s1) + (size_t)r * D_DIM;
        __hip_bfloat16* dst = (second ? s2b : s1b) + (size_t)r * D_DIM;
        float4 v = reinterpret_cast<const float4*>(src)[l];
        float s = v.x * v.x + v.y * v.y + v.z * v.z + v.w * v.w;
        bf16x4 bv;
        bv[0] = (__bf16)v.x; bv[1] = (__bf16)v.y; bv[2] = (__bf16)v.z; bv[3] = (__bf16)v.w;
        *reinterpret_cast<bf16x4*>(dst + l * 4) = bv;
#pragma unroll
        for (int o = 32; o > 0; o >>= 1) s += __shfl_xor(s, o, 64);
        if (l == 0) nrm[row] = s;
    }
}

// ---------------------------------------------------------------------------
// Persistent 2-tile GEMM (r9 skeleton) with DECOUPLED store overlap:
// All 4 LDS buffers are pre-staged before each tile's K-loop (and before the
// transition's 64 epilogue stores), so in-loop stages are stage(kt+3) at
// kt=1..4 and the FIRST vmem wait is at kt=3 (vmcnt(4)). Because vmcnt
// retires in-order, any wait forces older stores drained — moving the first
// wait from kt=1/2 (r9) to kt=3 gives the store burst ~3 extra K-steps to
// retire under compute before anything blocks on it.
// Per-step schedule (both tiles identical):
//   kt=3..5: vmcnt(4)   (stage(kt+1) landed; only stage(kt+2) in flight)
//   kt=6:    vmcnt(0)
//   kt>=1:   s_barrier  (publishes stages; orders buf overwrites)
//   kt<7:    readFrags(kt+1); lgkmcnt(8)  (drains frags(kt))
//   kt=1..4: stageK(kt+3)  (overwrites buf[(kt-1)&3]; its readers drained
//            by lgkm@kt-1 before barrier@kt -> safe, same induction as r9)
// Transition: stage 4 bufs -> vmcnt(0) -> barrier -> readFrags(0) (ds_reads
// overlap epilogue VALU) -> 64 fire-and-forget stores -> loop.
// ---------------------------------------------------------------------------
__global__ __launch_bounds__(256, 2) void dist_gemm2_kernel(const __hip_bfloat16* __restrict__ s1b,
                                                            const __hip_bfloat16* __restrict__ s2b,
                                                            const float* __restrict__ nrm,
                                                            float* __restrict__ out) {
    __shared__ __bf16 Alds[4][128 * 32];
    __shared__ __bf16 Blds[4][128 * 32];

    const int t = threadIdx.x;
    const int p = blockIdx.x;
    // XCD swizzle (512 blocks): XCD x owns d in [64x,64x+64) = batches 2x,2x+1.
    const int d = ((p & 7) << 6) + (p >> 3);
    const int batch = d >> 5;
    const int rem = d & 31;                    // 8 row-panels x 4 col-pairs
    const int row0 = (rem >> 2) << 7;
    const int col0a = (rem & 3) << 8;
    const int col0b = col0a + 128;

    const __hip_bfloat16* Ag = s1b + ((size_t)batch * L_DIM + row0) * D_DIM;
    const __hip_bfloat16* Bg0 = s2b + ((size_t)batch * L_DIM + col0a) * D_DIM;
    const __hip_bfloat16* Bg1 = s2b + ((size_t)batch * L_DIM + col0b) * D_DIM;

    const int l = t & 63, w = t >> 6;
    const int wr = w >> 1, wc = w & 1;   // wave -> 64x64 quadrant
    const int lr = l & 15;               // frag row (A) / col (B,C)
    const int lq = l >> 4;               // quarter = base 16B slot

    const int srow_in_seg = l >> 2;
    const int sslot = (l & 3) ^ ((l >> 3) & 3);

    auto stageK = [&](const __hip_bfloat16* Bg, int kt) {  // 4 gload_lds
        const int k0 = kt << 5;
        const int b = kt & 3;
#pragma unroll
        for (int i = 0; i < 2; ++i) {
            const int s = (w << 1) | i;
            const int rl = (s << 4) + srow_in_seg;
            GLOAD_LDS16(Ag + rl * D_DIM + k0 + sslot * 8, &Alds[b][s << 9]);
            GLOAD_LDS16(Bg + rl * D_DIM + k0 + sslot * 8, &Blds[b][s << 9]);
        }
    };

    bf16x8 aF[2][4], bF[2][4];
    auto readFrags = [&](int kt, bf16x8* a, bf16x8* bfr) {  // 8 ds_read_b128
        const int b = kt & 3;
#pragma unroll
        for (int m = 0; m < 4; ++m) {
            const int row = (wr << 6) + (m << 4) + lr;
            const int sl = lq ^ ((row >> 1) & 3);
            a[m] = *reinterpret_cast<const bf16x8*>(&Alds[b][(row << 5) + (sl << 3)]);
        }
#pragma unroll
        for (int n = 0; n < 4; ++n) {
            const int row = (wc << 6) + (n << 4) + lr;
            const int sl = lq ^ ((row >> 1) & 3);
            bfr[n] = *reinterpret_cast<const bf16x8*>(&Blds[b][(row << 5) + (sl << 3)]);
        }
    };

    const float* x2 = nrm + batch * L_DIM;
    const float* y2 = nrm + B_DIM * L_DIM + batch * L_DIM;
    const int rbase = row0 + (wr << 6) + (lq << 2);
    const int cloc = (wc << 6) + lr;
    float* outb = out + (size_t)batch * L_DIM * L_DIM;

    auto epilogue = [&](const f32x4 (&acc)[4][4], const f32x4 (&xv)[4],
                        const float (&yv)[4], int col0_) {
        const int cb = col0_ + cloc;
#pragma unroll
        for (int n = 0; n < 4; ++n) {
            const int col = cb + (n << 4);
            const float y2v = yv[n];
#pragma unroll
            for (int m = 0; m < 4; ++m) {
#pragma unroll
                for (int r = 0; r < 4; ++r) {
                    const int row = rbase + (m << 4) + r;
                    float sq = fmaxf(xv[m][r] + y2v - 2.0f * acc[m][n][r], 0.0f);
                    outb[(size_t)row * L_DIM + col] =
                        __builtin_amdgcn_rcpf(1.0f + __builtin_amdgcn_sqrtf(sq));
                }
            }
        }
    };

    // ===================== PROLOGUE ========================================
    f32x4 xv[4]; float yv0[4], yv1[4];
#pragma unroll
    for (int m = 0; m < 4; ++m) xv[m] = *reinterpret_cast<const f32x4*>(&x2[rbase + (m << 4)]);
#pragma unroll
    for (int n = 0; n < 4; ++n) yv0[n] = y2[col0a + cloc + (n << 4)];
#pragma unroll
    for (int n = 0; n < 4; ++n) yv1[n] = y2[col0b + cloc + (n << 4)];
    SBAR();
    f32x4 acc0[4][4] = {};
    stageK(Bg0, 0); stageK(Bg0, 1); stageK(Bg0, 2); stageK(Bg0, 3);
    SBAR();
    asm volatile("s_waitcnt vmcnt(0)" ::: "memory");   // all 4 bufs + norms landed
    __builtin_amdgcn_s_barrier();
    readFrags(0, aF[0], bF[0]);

    // ===================== TILE 0 K-LOOP ===================================
#pragma unroll
    for (int kt = 0; kt < 8; ++kt) {
        if (kt >= 3 && kt <= 5) asm volatile("s_waitcnt vmcnt(4)" ::: "memory");
        else if (kt == 6)       asm volatile("s_waitcnt vmcnt(0)" ::: "memory");
        if (kt >= 1) __builtin_amdgcn_s_barrier();
        if (kt < 7) readFrags(kt + 1, aF[(kt + 1) & 1], bF[(kt + 1) & 1]);
        if (kt < 7) asm volatile("s_waitcnt lgkmcnt(8)" ::: "memory");
        else        asm volatile("s_waitcnt lgkmcnt(0)" ::: "memory");
        if (kt >= 1 && kt <= 4) stageK(Bg0, kt + 3);
        __builtin_amdgcn_s_setprio(1);
#pragma unroll
        for (int m = 0; m < 4; ++m)
#pragma unroll
            for (int n = 0; n < 4; ++n)
                acc0[m][n] = __builtin_amdgcn_mfma_f32_16x16x32_bf16(
                    aF[kt & 1][m], bF[kt & 1][n], acc0[m][n], 0, 0, 0);
        __builtin_amdgcn_s_setprio(0);
    }

    // ===================== TRANSITION ======================================
    // (loop0 kt=6 did vmcnt(0): nothing outstanding here but the new stages)
    stageK(Bg1, 0); stageK(Bg1, 1); stageK(Bg1, 2); stageK(Bg1, 3);
    SBAR();
    asm volatile("s_waitcnt vmcnt(0)" ::: "memory");   // all 4 bufs landed
    __builtin_amdgcn_s_barrier();
    readFrags(0, aF[0], bF[0]);       // ds_reads overlap epilogue VALU below
    epilogue(acc0, xv, yv0, col0a);   // 64 fire-and-forget stores
    SBAR();
    f32x4 acc1[4][4] = {};

    // ===================== TILE 1 K-LOOP ===================================
    // vmcnt(4)@kt=3 is the FIRST wait that can touch the stores: they get
    // kt=0..2 (+transition) to retire under compute before anything blocks.
#pragma unroll
    for (int kt = 0; kt < 8; ++kt) {
        if (kt >= 3 && kt <= 5) asm volatile("s_waitcnt vmcnt(4)" ::: "memory");
        else if (kt == 6)       asm volatile("s_waitcnt vmcnt(0)" ::: "memory");
        if (kt >= 1) __builtin_amdgcn_s_barrier();
        if (kt < 7) readFrags(kt + 1, aF[(kt + 1) & 1], bF[(kt + 1) & 1]);
        if (kt < 7) asm volatile("s_waitcnt lgkmcnt(8)" ::: "memory");
        else        asm volatile("s_waitcnt lgkmcnt(0)" ::: "memory");
        if (kt >= 1 && kt <= 4) stageK(Bg1, kt + 3);
        __builtin_amdgcn_s_setprio(1);
#pragma unroll
        for (int m = 0; m < 4; ++m)
#pragma unroll
            for (int n = 0; n < 4; ++n)
                acc1[m][n] = __builtin_amdgcn_mfma_f32_16x16x32_bf16(
                    aF[kt & 1][m], bF[kt & 1][n], acc1[m][n], 0, 0, 0);
        __builtin_amdgcn_s_setprio(0);
    }

    epilogue(acc1, xv, yv1, col0b);
}

// ---------------------------------------------------------------------------
// Fallback path for the case ws_size < needed.
// ---------------------------------------------------------------------------
__global__ __launch_bounds__(256) void norms_kernel(const float* __restrict__ s1,
                                                    const float* __restrict__ s2,
                                                    float* __restrict__ nrm) {
    int w = threadIdx.x >> 6, l = threadIdx.x & 63;
    int row = (blockIdx.x << 2) + w;
    const float* src = (row < B_DIM * L_DIM)
                           ? (s1 + (size_t)row * D_DIM)
                           : (s2 + (size_t)(row - B_DIM * L_DIM) * D_DIM);
    float4 v = reinterpret_cast<const float4*>(src)[l];
    float s = v.x * v.x + v.y * v.y + v.z * v.z + v.w * v.w;
#pragma unroll
    for (int o = 32; o > 0; o >>= 1) s += __shfl_xor(s, o, 64);
    if (l == 0) nrm[row] = s;
}

__global__ __launch_bounds__(256) void dist_gemm_kernel(const float* __restrict__ s1,
                                                        const float* __restrict__ s2,
                                                        const float* __restrict__ nrm,
                                                        float* __restrict__ out) {
    __shared__ __bf16 Alds[2][128 * 32];
    __shared__ __bf16 Blds[2][128 * 32];

    const int t = threadIdx.x;
    const int p = blockIdx.x;
    const int d = ((p & 7) << 7) + (p >> 3);
    const int batch = d >> 6;
    const int tile = d & 63;
    const int row0 = (tile >> 3) << 7;
    const int col0 = (tile & 7) << 7;

    const float* Ag = s1 + ((size_t)batch * L_DIM + row0) * D_DIM;
    const float* Bg = s2 + ((size_t)batch * L_DIM + col0) * D_DIM;

    const int sr = t >> 2;
    const int sc = (t & 3) << 3;

    const int l = t & 63, w = t >> 6;
    const int wr = w >> 1, wc = w & 1;
    const int lr = l & 15;
    const int lk = (l >> 4) << 3;

    f32x4 acc[4][4] = {};

    auto stage = [&](int buf, int k0) {
#pragma unroll
        for (int pass = 0; pass < 2; ++pass) {
            const int r = sr + (pass << 6);
            const float4* sa = reinterpret_cast<const float4*>(Ag + (size_t)r * D_DIM + k0 + sc);
            float4 a0 = sa[0], a1 = sa[1];
            const float4* sb = reinterpret_cast<const float4*>(Bg + (size_t)r * D_DIM + k0 + sc);
            float4 b0 = sb[0], b1 = sb[1];
            bf16x8 av, bv;
            av[0] = (__bf16)a0.x; av[1] = (__bf16)a0.y; av[2] = (__bf16)a0.z; av[3] = (__bf16)a0.w;
            av[4] = (__bf16)a1.x; av[5] = (__bf16)a1.y; av[6] = (__bf16)a1.z; av[7] = (__bf16)a1.w;
            bv[0] = (__bf16)b0.x; bv[1] = (__bf16)b0.y; bv[2] = (__bf16)b0.z; bv[3] = (__bf16)b0.w;
            bv[4] = (__bf16)b1.x; bv[5] = (__bf16)b1.y; bv[6] = (__bf16)b1.z; bv[7] = (__bf16)b1.w;
            *reinterpret_cast<bf16x8*>(&Alds[buf][(r << 5) + sc]) = av;
            *reinterpret_cast<bf16x8*>(&Blds[buf][(r << 5) + sc]) = bv;
        }
    };

    stage(0, 0);
    __syncthreads();
    int cur = 0;
    for (int kt = 0; kt < 8; ++kt) {
        if (kt < 7) stage(cur ^ 1, (kt + 1) << 5);
        bf16x8 aF[4], bF[4];
#pragma unroll
        for (int m = 0; m < 4; ++m)
            aF[m] = *reinterpret_cast<const bf16x8*>(
                &Alds[cur][(((wr << 6) + (m << 4) + lr) << 5) + lk]);
#pragma unroll
        for (int n = 0; n < 4; ++n)
            bF[n] = *reinterpret_cast<const bf16x8*>(
                &Blds[cur][(((wc << 6) + (n << 4) + lr) << 5) + lk]);
#pragma unroll
        for (int m = 0; m < 4; ++m)
#pragma unroll
            for (int n = 0; n < 4; ++n)
                acc[m][n] = __builtin_amdgcn_mfma_f32_16x16x32_bf16(aF[m], bF[n], acc[m][n], 0, 0, 0);
        __syncthreads();
        cur ^= 1;
    }

    const float* x2 = nrm + batch * L_DIM;
    const float* y2 = nrm + B_DIM * L_DIM + batch * L_DIM;
    float* outb = out + (size_t)batch * L_DIM * L_DIM;
    const int rbase = row0 + (wr << 6) + ((l >> 4) << 2);
    const int cbase = col0 + (wc << 6) + lr;
#pragma unroll
    for (int n = 0; n < 4; ++n) {
        const int col = cbase + (n << 4);
        const float y2v = y2[col];
#pragma unroll
        for (int m = 0; m < 4; ++m) {
            const int rowf = rbase + (m << 4);
#pragma unroll
            for (int r = 0; r < 4; ++r) {
                const int row = rowf + r;
                float sq = x2[row] + y2v - 2.0f * acc[m][n][r];
                sq = fmaxf(sq, 0.0f);
                outb[(size_t)row * L_DIM + col] = 1.0f / (1.0f + sqrtf(sq));
            }
        }
    }
}

extern "C" void kernel_launch(void* const* d_in, const int* in_sizes, int n_in,
                              void* d_out, int out_size, void* d_ws, size_t ws_size,
                              hipStream_t stream) {
    (void)in_sizes; (void)n_in; (void)out_size;
    const float* s1 = (const float*)d_in[1];
    const float* s2 = (const float*)d_in[2];
    float* out = (float*)d_out;

    const size_t NRM_BYTES = 2u * B_DIM * L_DIM * sizeof(float);          // 128 KB
    const size_t BF_BYTES = (size_t)B_DIM * L_DIM * D_DIM * sizeof(__hip_bfloat16);  // 8 MB each
    const size_t NEED = NRM_BYTES + 2 * BF_BYTES;                          // ~16.9 MB

    float* nrm = (float*)d_ws;
    if (ws_size >= NEED) {
        __hip_bfloat16* s1b = (__hip_bfloat16*)((char*)d_ws + NRM_BYTES);
        __hip_bfloat16* s2b = (__hip_bfloat16*)((char*)d_ws + NRM_BYTES + BF_BYTES);
        prep_kernel<<<2048, 256, 0, stream>>>(s1, s2, nrm, s1b, s2b);
        dist_gemm2_kernel<<<512, 256, 0, stream>>>(s1b, s2b, nrm, out);
    } else {
        norms_kernel<<<8192, 256, 0, stream>>>(s1, s2, nrm);
        dist_gemm_kernel<<<1024, 256, 0, stream>>>(s1, s2, nrm, out);
    }
}